// Round 14
// baseline (370.925 us; speedup 1.0000x reference)
//
#include <hip/hip_runtime.h>
#include <hip/hip_fp16.h>
#include <stdint.h>

#define B_ 32
#define T_ 4096
#define P_ 512
#define W_ 128
#define NMEL 80
#define FILT 256
#define PDIM 64
#define KW 9
#define TP8 (T_ + 8)
#define MSTR 104
#define YSTR 264
#define EPS 1e-5f

typedef unsigned short u16;
typedef __attribute__((ext_vector_type(8))) short short8;
typedef __attribute__((ext_vector_type(8))) _Float16 half8;
typedef __attribute__((ext_vector_type(4))) float f32x4;
typedef __attribute__((ext_vector_type(16))) float f32x16;

typedef const __attribute__((address_space(1))) uint32_t* gptr_t;
typedef __attribute__((address_space(3))) uint32_t* lptr_t;

__device__ __forceinline__ u16 f2h(float v){ return __half_as_ushort(__float2half(v)); }

#define MFMA32(accv, av, bv) \
  accv = __builtin_amdgcn_mfma_f32_32x32x16_f16((av), (bv), (accv), 0, 0, 0)

// one k32 step for wave tile 128x64: 12 loads, 16 MFMAs.
// A fragments: first k16 half at pA, second at pA+16 (u16 elems).
#define K32_BODY(pA, STR) { \
    half8 a0 = *(const half8*)(pA); \
    half8 g0 = *(const half8*)((pA) + 16); \
    half8 a1 = *(const half8*)((pA) + 32*STR); \
    half8 g1 = *(const half8*)((pA) + 32*STR + 16); \
    half8 a2 = *(const half8*)((pA) + 64*STR); \
    half8 g2 = *(const half8*)((pA) + 64*STR + 16); \
    half8 a3 = *(const half8*)((pA) + 96*STR); \
    half8 g3 = *(const half8*)((pA) + 96*STR + 16); \
    half8 b00 = *(const half8*)(gBp); \
    half8 b01 = *(const half8*)(gBp + 512); \
    half8 b10 = *(const half8*)(gBp + 8192); \
    half8 b11 = *(const half8*)(gBp + 8704); \
    gBp += 16384; \
    MFMA32(acc[0][0], a0, b00); MFMA32(acc[0][1], a0, b01); \
    MFMA32(acc[1][0], a1, b00); MFMA32(acc[1][1], a1, b01); \
    MFMA32(acc[2][0], a2, b00); MFMA32(acc[2][1], a2, b01); \
    MFMA32(acc[3][0], a3, b00); MFMA32(acc[3][1], a3, b01); \
    MFMA32(acc[0][0], g0, b10); MFMA32(acc[0][1], g0, b11); \
    MFMA32(acc[1][0], g1, b10); MFMA32(acc[1][1], g1, b11); \
    MFMA32(acc[2][0], g2, b10); MFMA32(acc[2][1], g2, b11); \
    MFMA32(acc[3][0], g3, b10); MFMA32(acc[3][1], g3, b11); }

// ---------------- prep: pack conv weights to [tap][kg][cout][8] fp16 ----------------
__global__ void pack_w(const float* __restrict__ w1, const float* __restrict__ w2,
                       u16* __restrict__ Wp1, u16* __restrict__ Wp2){
  int i = blockIdx.x * 256 + threadIdx.x;
  const int N1 = KW * 12 * FILT;          // 27648
  const int N2 = KW * 32 * FILT;          // 73728
  if (i < N1){
    int tap = i / (12*FILT); int r = i - tap*12*FILT; int kg = r / FILT; int co = r - kg*FILT;
    short8 v;
    #pragma unroll
    for (int e=0;e<8;e++){
      int ci = kg*8 + e;
      float x = (ci < NMEL) ? w1[(co*NMEL + ci)*KW + tap] : 0.f;
      v[e] = (short)f2h(x);
    }
    *(short8*)(Wp1 + (size_t)i*8) = v;
  } else if (i < N1 + N2){
    int j = i - N1;
    int tap = j / (32*FILT); int r = j - tap*32*FILT; int kg = r / FILT; int co = r - kg*FILT;
    short8 v;
    #pragma unroll
    for (int e=0;e<8;e++){
      int ci = kg*8 + e;
      v[e] = (short)f2h(w2[(co*FILT + ci)*KW + tap]);
    }
    *(short8*)(Wp2 + (size_t)j*8) = v;
  }
}

// ---------------- prep: mels -> padded fp16 [B][T+8][104], vectorized ----------------
__global__ void prep_mels(const float* __restrict__ mels, u16* __restrict__ melsPad){
  int idx = blockIdx.x * 256 + threadIdx.x;
  if (idx >= B_*TP8*13) return;
  int ch = idx % 13; int r = idx / 13; int row = r % TP8; int b = r / TP8;
  int t = row - 4;
  short8 v = (short8){0,0,0,0,0,0,0,0};
  if (t >= 0 && t < T_ && ch < 10){
    const float* src = mels + ((size_t)b*T_ + t)*NMEL + ch*8;
    const f32x4 f0 = *(const f32x4*)src;
    const f32x4 f1 = *(const f32x4*)(src+4);
    #pragma unroll
    for (int j=0;j<4;j++){ v[j]=(short)f2h(f0[j]); v[4+j]=(short)f2h(f1[j]); }
  }
  *(short8*)(melsPad + (size_t)idx*8) = v;
}

// ---------------- prep: cumsums (LDS scan), frame->phone, phone->word, zero y1 halos ----------------
__global__ void prep_seg(const int* __restrict__ dur, const int* __restrict__ wpl,
                         int* __restrict__ wcum,
                         int* __restrict__ pid, int* __restrict__ wid,
                         u16* __restrict__ y1Pad){
  int b = blockIdx.x; int tid = threadIdx.x;
  __shared__ int dc[P_];
  __shared__ int wc[W_];
  for (int p=tid; p<P_; p+=256) dc[p] = dur[b*P_+p];
  if (tid < W_) wc[tid] = wpl[b*W_+tid];
  __syncthreads();
  if (tid == 0){ int run=0; for (int p=0;p<P_;p++){ run += dc[p]; dc[p]=run; } }
  if (tid == 64){ int run=0; for (int w=0;w<W_;w++){ run += wc[w]; wc[w]=run; wcum[b*W_+w]=run; } }
  __syncthreads();
  for (int t=tid; t<T_; t+=256){
    int lo=0, hi=P_;
    while (lo < hi){ int mid=(lo+hi)>>1; if (dc[mid] > t) hi=mid; else lo=mid+1; }
    pid[b*T_+t] = lo;
  }
  for (int p=tid; p<P_; p+=256){
    int lo=0, hi=W_;
    while (lo < hi){ int mid=(lo+hi)>>1; if (wc[mid] > p) hi=mid; else lo=mid+1; }
    wid[b*P_+p] = min(lo, W_-1);
  }
  for (int i=tid; i<8*YSTR; i+=256){
    int rr = i / YSTR; int cc = i - rr*YSTR;
    int row = (rr < 4) ? rr : (T_ + rr);
    y1Pad[((size_t)b*TP8 + row)*YSTR + cc] = 0;
  }
}

// ---------------- conv1 + bias + relu + LN1 -> y1Pad fp16 ----------------
// M=256, 512 thr / 8 waves, wave tile 128x64. A in LDS once; B direct
// global->reg. K-loop start rotated per (block,wave) to decorrelate the
// chip-wide B L2 stream and anti-phase co-resident waves.
__global__ __launch_bounds__(512, 2) void conv1_k(
    const u16* __restrict__ melsPad, const u16* __restrict__ Wp1,
    const float* __restrict__ bias, const float* __restrict__ lng,
    const float* __restrict__ lnb, u16* __restrict__ y1Pad){
  __shared__ __align__(16) u16 sA[27456];   // 54,912 B: 264 rows x 104
  const int tid = threadIdx.x;
  const int wave = tid >> 6, lane = tid & 63, l31 = lane & 31, h = lane >> 5;
  const int rg = wave >> 2, cg = wave & 3;
  const int b = blockIdx.y, t0 = blockIdx.x * 256;

  float bcol[2], gcol[2], btcol[2];
  #pragma unroll
  for (int n=0;n<2;n++){
    int c = cg*64 + n*32 + l31;
    bcol[n]=bias[c]; gcol[n]=lng[c]; btcol[n]=lnb[c];
  }

  {
    const char* gA = (const char*)(melsPad + ((size_t)b*TP8 + t0)*MSTR);
    #pragma unroll
    for (int it=0; it<7; ++it)
      if (it*8192 + tid*16 < 54912)
        __builtin_amdgcn_global_load_lds((gptr_t)(gA + it*8192 + (wave<<10) + (lane<<4)),
                                         (lptr_t)((char*)sA + it*8192 + (wave<<10)), 16, 0, 0);
  }
  const char* gB0 = (const char*)Wp1 + h*4096 + cg*1024 + (l31<<4);
  __syncthreads();   // A resident

  f32x16 acc[4][2] = {};
  const u16* pA0 = sA + ((size_t)(rg*128 + l31))*MSTR + h*8;
  const int start = ((blockIdx.x*5 + wave) % 9) * 3;   // 0,3,...,24

  const char* gBp = gB0 + (size_t)start*16384;
  #pragma unroll 1
  for (int k=start; k<27; ++k){
    const int tap = k/3, s = k - tap*3;
    const u16* pA = pA0 + tap*MSTR + s*32;
    K32_BODY(pA, MSTR)
  }
  gBp = gB0;
  #pragma unroll 1
  for (int k=0; k<start; ++k){
    const int tap = k/3, s = k - tap*3;
    const u16* pA = pA0 + tap*MSTR + s*32;
    K32_BODY(pA, MSTR)
  }

  float* sred  = (float*)sA;          // [256][4]
  float* sred2 = sred + 1024;
  float* smean = sred2 + 1024;        // [256]
  float* srstd = smean + 256;
  __syncthreads();   // all waves done reading sA

  #pragma unroll
  for (int rb=0;rb<4;++rb)
    #pragma unroll
    for (int r=0;r<16;++r){
      float v0 = fmaxf(acc[rb][0][r] + bcol[0], 0.f);
      float v1 = fmaxf(acc[rb][1][r] + bcol[1], 0.f);
      float s = v0+v1, q = v0*v0+v1*v1;
      #pragma unroll
      for (int off=1; off<32; off<<=1){ s += __shfl_xor(s, off); q += __shfl_xor(q, off); }
      if (l31 == 0){ int row = rg*128 + rb*32 + (r&3) + 8*(r>>2) + 4*h;
        sred[row*4+cg]=s; sred2[row*4+cg]=q; }
    }
  __syncthreads();
  if (tid < 256){
    float ss=0.f, qq=0.f;
    #pragma unroll
    for (int w2=0; w2<4; w2++){ ss += sred[tid*4+w2]; qq += sred2[tid*4+w2]; }
    float mean = ss * (1.f/FILT);
    float var  = qq * (1.f/FILT) - mean*mean;
    smean[tid] = mean;
    srstd[tid] = rsqrtf(fmaxf(var, 0.f) + EPS);
  }
  __syncthreads();

  #pragma unroll
  for (int rb=0;rb<4;++rb)
    #pragma unroll
    for (int q=0;q<4;++q){
      const int rbase = rg*128 + rb*32 + q*8 + 4*h;
      float mn0=smean[rbase+0],mn1=smean[rbase+1],mn2=smean[rbase+2],mn3=smean[rbase+3];
      float rs0=srstd[rbase+0],rs1=srstd[rbase+1],rs2=srstd[rbase+2],rs3=srstd[rbase+3];
      #pragma unroll
      for (int cb=0;cb<2;++cb){
        int c = cg*64 + cb*32 + l31;
        float x0 = fmaxf(acc[rb][cb][q*4+0] + bcol[cb], 0.f);
        float x1 = fmaxf(acc[rb][cb][q*4+1] + bcol[cb], 0.f);
        float x2 = fmaxf(acc[rb][cb][q*4+2] + bcol[cb], 0.f);
        float x3 = fmaxf(acc[rb][cb][q*4+3] + bcol[cb], 0.f);
        u16* dst = y1Pad + ((size_t)b*TP8 + 4 + t0 + rbase)*YSTR + c;
        dst[0*YSTR] = f2h((x0-mn0)*rs0*gcol[cb]+btcol[cb]);
        dst[1*YSTR] = f2h((x1-mn1)*rs1*gcol[cb]+btcol[cb]);
        dst[2*YSTR] = f2h((x2-mn2)*rs2*gcol[cb]+btcol[cb]);
        dst[3*YSTR] = f2h((x3-mn3)*rs3*gcol[cb]+btcol[cb]);
      }
    }
}

// ---------------- conv2 + bias + relu + LN2 -> phone-sum atomics ----------------
// M=256, 512 thr / 8 waves, wave tile 128x64. A (139.4 KB) in LDS once;
// B direct global->reg; rotated K-start per (block,wave).
__global__ __launch_bounds__(512, 2) void conv2_k(
    const u16* __restrict__ y1Pad, const u16* __restrict__ Wp2,
    const float* __restrict__ bias, const float* __restrict__ lng,
    const float* __restrict__ lnb, const int* __restrict__ pid,
    float* __restrict__ ps){
  __shared__ __align__(16) u16 sA[69696];   // 139,392 B: 264 rows x 264
  __shared__ int pidT[256];
  const int tid = threadIdx.x;
  const int wave = tid >> 6, lane = tid & 63, l31 = lane & 31, h = lane >> 5;
  const int rg = wave >> 2, cg = wave & 3;
  const int b = blockIdx.y, t0 = blockIdx.x * 256;

  float bcol[2], gcol[2], btcol[2];
  #pragma unroll
  for (int n=0;n<2;n++){
    int c = cg*64 + n*32 + l31;
    bcol[n]=bias[c]; gcol[n]=lng[c]; btcol[n]=lnb[c];
  }
  if (tid < 256) pidT[tid] = pid[b*T_ + t0 + tid];

  {
    const char* gA = (const char*)(y1Pad + ((size_t)b*TP8 + t0)*YSTR);
    #pragma unroll
    for (int it=0; it<18; ++it)
      if (it*8192 + tid*16 < 139392)
        __builtin_amdgcn_global_load_lds((gptr_t)(gA + it*8192 + (wave<<10) + (lane<<4)),
                                         (lptr_t)((char*)sA + it*8192 + (wave<<10)), 16, 0, 0);
  }
  const char* gB0 = (const char*)Wp2 + h*4096 + cg*1024 + (l31<<4);
  __syncthreads();   // A resident

  f32x16 acc[4][2] = {};
  const u16* pA0 = sA + ((size_t)(rg*128 + l31))*YSTR + h*8;
  const int start = ((blockIdx.x*5 + wave) & 7) * 9;   // 0,9,...,63

  const char* gBp = gB0 + (size_t)start*16384;
  #pragma unroll 2
  for (int k=start; k<72; ++k){
    const int tap = k>>3, sg = k&7;
    const u16* pA = pA0 + tap*YSTR + sg*32;
    K32_BODY(pA, YSTR)
  }
  gBp = gB0;
  #pragma unroll 2
  for (int k=0; k<start; ++k){
    const int tap = k>>3, sg = k&7;
    const u16* pA = pA0 + tap*YSTR + sg*32;
    K32_BODY(pA, YSTR)
  }

  float* sred  = (float*)sA;          // [256][4]
  float* sred2 = sred + 1024;
  float* smean = sred2 + 1024;        // [256]
  float* srstd = smean + 256;
  __syncthreads();   // all waves done reading sA

  #pragma unroll
  for (int rb=0;rb<4;++rb)
    #pragma unroll
    for (int r=0;r<16;++r){
      float v0 = fmaxf(acc[rb][0][r] + bcol[0], 0.f);
      float v1 = fmaxf(acc[rb][1][r] + bcol[1], 0.f);
      float s = v0+v1, q = v0*v0+v1*v1;
      #pragma unroll
      for (int off=1; off<32; off<<=1){ s += __shfl_xor(s, off); q += __shfl_xor(q, off); }
      if (l31 == 0){ int row = rg*128 + rb*32 + (r&3) + 8*(r>>2) + 4*h;
        sred[row*4+cg]=s; sred2[row*4+cg]=q; }
    }
  __syncthreads();
  if (tid < 256){
    float ss=0.f, qq=0.f;
    #pragma unroll
    for (int w2=0; w2<4; w2++){ ss += sred[tid*4+w2]; qq += sred2[tid*4+w2]; }
    float mean = ss * (1.f/FILT);
    float var  = qq * (1.f/FILT) - mean*mean;
    smean[tid] = mean;
    srstd[tid] = rsqrtf(fmaxf(var, 0.f) + EPS);
  }
  __syncthreads();

  #pragma unroll
  for (int rb=0;rb<4;++rb)
    #pragma unroll
    for (int q=0;q<4;++q){
      const int rbase = rg*128 + rb*32 + q*8 + 4*h;
      int p0v = pidT[rbase]; int fold = (p0v == pidT[rbase+3]);
      float mn0=smean[rbase+0],mn1=smean[rbase+1],mn2=smean[rbase+2],mn3=smean[rbase+3];
      float rs0=srstd[rbase+0],rs1=srstd[rbase+1],rs2=srstd[rbase+2],rs3=srstd[rbase+3];
      int pp = __shfl_xor(p0v, 32); int fp = __shfl_xor(fold, 32);
      #pragma unroll
      for (int cb=0;cb<2;++cb){
        int c = cg*64 + cb*32 + l31;
        float x0 = fmaxf(acc[rb][cb][q*4+0] + bcol[cb], 0.f);
        float x1 = fmaxf(acc[rb][cb][q*4+1] + bcol[cb], 0.f);
        float x2 = fmaxf(acc[rb][cb][q*4+2] + bcol[cb], 0.f);
        float x3 = fmaxf(acc[rb][cb][q*4+3] + bcol[cb], 0.f);
        float o0 = (x0-mn0)*rs0*gcol[cb]+btcol[cb];
        float o1 = (x1-mn1)*rs1*gcol[cb]+btcol[cb];
        float o2 = (x2-mn2)*rs2*gcol[cb]+btcol[cb];
        float o3 = (x3-mn3)*rs3*gcol[cb]+btcol[cb];
        float s4 = fold ? (o0+o1+o2+o3) : 0.f;
        float sp = __shfl_xor(s4, 32);
        float* basep = ps + (size_t)b*P_*FILT;
        if (fold){
          if (p0v < P_){
            if (fp && pp == p0v){ if (h == 0) atomicAdd(basep + (size_t)p0v*FILT + c, s4 + sp); }
            else atomicAdd(basep + (size_t)p0v*FILT + c, s4);
          }
        } else {
          int pj;
          pj = pidT[rbase+0]; if (pj < P_) atomicAdd(basep + (size_t)pj*FILT + c, o0);
          pj = pidT[rbase+1]; if (pj < P_) atomicAdd(basep + (size_t)pj*FILT + c, o1);
          pj = pidT[rbase+2]; if (pj < P_) atomicAdd(basep + (size_t)pj*FILT + c, o2);
          pj = pidT[rbase+3]; if (pj < P_) atomicAdd(basep + (size_t)pj*FILT + c, o3);
        }
      }
    }
}

// ---------------- word pooling + MLP: 8 words per block ----------------
#define WPB 8
__global__ __launch_bounds__(256) void word_k(
    const float* __restrict__ ps, const int* __restrict__ dur,
    const int* __restrict__ wcum, const int* __restrict__ wpl,
    const float* __restrict__ w1, const float* __restrict__ b1,
    const float* __restrict__ w2, const float* __restrict__ b2,
    float* __restrict__ wemb){
  int b = blockIdx.y, wg = blockIdx.x * WPB, tid = threadIdx.x;
  __shared__ float wvS[WPB][FILT];
  __shared__ float h1S[WPB][FILT];
  #pragma unroll
  for (int k=0;k<WPB;k++){
    int w = wg + k;
    int p1 = wcum[b*W_ + w]; int p0 = (w == 0) ? 0 : wcum[b*W_ + w - 1];
    if (p1 > P_) p1 = P_;
    int len = wpl[b*W_ + w];
    float a = 0.f;
    for (int p = p0; p < p1; ++p){
      int d = dur[b*P_ + p]; d = d < 1 ? 1 : d;
      a += ps[((size_t)(b*P_ + p))*FILT + tid] / (float)d;
    }
    wvS[k][tid] = a / (float)(len < 1 ? 1 : len);
  }
  __syncthreads();
  float acc[WPB];
  #pragma unroll
  for (int k=0;k<WPB;k++) acc[k] = b1[tid];
  for (int i=0;i<FILT;i++){
    float wcol = w1[i*FILT + tid];
    #pragma unroll
    for (int k=0;k<WPB;k++) acc[k] += wvS[k][i] * wcol;
  }
  #pragma unroll
  for (int k=0;k<WPB;k++) h1S[k][tid] = fmaxf(acc[k], 0.f);
  __syncthreads();
  int c = tid & 63, kq = tid >> 6;
  #pragma unroll
  for (int kk=kq; kk<WPB; kk+=4){
    float u = b2[c];
    for (int i=0;i<FILT;i++) u += h1S[kk][i] * w2[i*PDIM + c];
    wemb[((size_t)(b*W_ + wg + kk))*PDIM + c] = fmaxf(u, 0.f);
  }
}

// ---------------- expand words -> phones + mask (float4) ----------------
__global__ void expand_k(const float* __restrict__ wemb, const int* __restrict__ wid,
                         const unsigned char* __restrict__ mask, float* __restrict__ out){
  int idx = blockIdx.x * 256 + threadIdx.x;
  if (idx >= B_*P_*16) return;
  int q = idx & 15; int p = (idx >> 4) & 511; int bb = idx >> 13;
  int w = wid[bb*P_ + p];
  f32x4 v = *(const f32x4*)(wemb + ((size_t)(bb*W_ + w))*PDIM + q*4);
  if (mask[bb*P_ + p]) v = (f32x4){0.f,0.f,0.f,0.f};
  *(f32x4*)(out + (size_t)idx*4) = v;
}

extern "C" void kernel_launch(void* const* d_in, const int* in_sizes, int n_in,
                              void* d_out, int out_size, void* d_ws, size_t ws_size,
                              hipStream_t stream) {
  const unsigned char* mask = (const unsigned char*)d_in[0];
  const float* mels = (const float*)d_in[1];
  const int*   dur  = (const int*)d_in[3];
  const int*   wpl  = (const int*)d_in[4];
  const float* c1w  = (const float*)d_in[5];
  const float* c1b  = (const float*)d_in[6];
  const float* l1g  = (const float*)d_in[7];
  const float* l1b  = (const float*)d_in[8];
  const float* c2w  = (const float*)d_in[9];
  const float* c2b  = (const float*)d_in[10];
  const float* l2g  = (const float*)d_in[11];
  const float* l2b  = (const float*)d_in[12];
  const float* w1   = (const float*)d_in[13];
  const float* b1   = (const float*)d_in[14];
  const float* w2   = (const float*)d_in[15];
  const float* b2   = (const float*)d_in[16];

  char* ws = (char*)d_ws;
  size_t off = 0;
  auto alloc = [&](size_t bytes){ void* p = ws + off; off += (bytes + 255) & ~(size_t)255; return p; };
  u16* melsPad = (u16*)alloc((size_t)B_*TP8*MSTR*2 + 32768);
  u16* y1Pad   = (u16*)alloc((size_t)B_*TP8*YSTR*2 + 32768);
  u16* Wp1     = (u16*)alloc((size_t)KW*12*FILT*8*2 + 32768);
  u16* Wp2     = (u16*)alloc((size_t)KW*32*FILT*8*2 + 32768);
  int* wcum    = (int*)alloc((size_t)B_*W_*4);
  int* pid     = (int*)alloc((size_t)B_*T_*4);
  int* wid     = (int*)alloc((size_t)B_*P_*4);
  float* psum  = (float*)alloc((size_t)B_*P_*FILT*4);
  float* wemb  = (float*)alloc((size_t)B_*W_*PDIM*4);

  hipMemsetAsync(psum, 0, (size_t)B_*P_*FILT*4, stream);
  pack_w<<<(KW*12*FILT + KW*32*FILT + 255)/256, 256, 0, stream>>>(c1w, c2w, Wp1, Wp2);
  prep_mels<<<(B_*TP8*13 + 255)/256, 256, 0, stream>>>(mels, melsPad);
  prep_seg<<<B_, 256, 0, stream>>>(dur, wpl, wcum, pid, wid, y1Pad);
  conv1_k<<<dim3(T_/256, B_), 512, 0, stream>>>(melsPad, Wp1, c1b, l1g, l1b, y1Pad);
  conv2_k<<<dim3(T_/256, B_), 512, 0, stream>>>(y1Pad, Wp2, c2b, l2g, l2b, pid, psum);
  word_k<<<dim3(W_/WPB, B_), 256, 0, stream>>>(psum, dur, wcum, wpl, w1, b1, w2, b2, wemb);
  expand_k<<<(B_*P_*16 + 255)/256, 256, 0, stream>>>(wemb, wid, mask, (float*)d_out);
}

// Round 15
// 367.731 us; speedup vs baseline: 1.0087x; 1.0087x over previous
//
#include <hip/hip_runtime.h>
#include <hip/hip_fp16.h>
#include <stdint.h>

#define B_ 32
#define T_ 4096
#define P_ 512
#define W_ 128
#define NMEL 80
#define FILT 256
#define PDIM 64
#define KW 9
#define TP8 (T_ + 8)
#define MSTR 104
#define YSTR 264
#define EPS 1e-5f

typedef unsigned short u16;
typedef __attribute__((ext_vector_type(8))) short short8;
typedef __attribute__((ext_vector_type(8))) _Float16 half8;
typedef __attribute__((ext_vector_type(4))) float f32x4;
typedef __attribute__((ext_vector_type(16))) float f32x16;

typedef const __attribute__((address_space(1))) uint32_t* gptr_t;
typedef __attribute__((address_space(3))) uint32_t* lptr_t;

__device__ __forceinline__ u16 f2h(float v){ return __half_as_ushort(__float2half(v)); }

#define MFMA32(accv, av, bv) \
  accv = __builtin_amdgcn_mfma_f32_32x32x16_f16((av), (bv), (accv), 0, 0, 0)

// one k32 step for wave tile 128x64: 12 loads, 16 MFMAs wrapped in setprio (T5).
#define K32_BODY(pA, STR) { \
    half8 a0 = *(const half8*)(pA); \
    half8 g0 = *(const half8*)((pA) + 16); \
    half8 a1 = *(const half8*)((pA) + 32*STR); \
    half8 g1 = *(const half8*)((pA) + 32*STR + 16); \
    half8 a2 = *(const half8*)((pA) + 64*STR); \
    half8 g2 = *(const half8*)((pA) + 64*STR + 16); \
    half8 a3 = *(const half8*)((pA) + 96*STR); \
    half8 g3 = *(const half8*)((pA) + 96*STR + 16); \
    half8 b00 = *(const half8*)(gBp); \
    half8 b01 = *(const half8*)(gBp + 512); \
    half8 b10 = *(const half8*)(gBp + 8192); \
    half8 b11 = *(const half8*)(gBp + 8704); \
    gBp += 16384; \
    __builtin_amdgcn_s_setprio(1); \
    MFMA32(acc[0][0], a0, b00); MFMA32(acc[0][1], a0, b01); \
    MFMA32(acc[1][0], a1, b00); MFMA32(acc[1][1], a1, b01); \
    MFMA32(acc[2][0], a2, b00); MFMA32(acc[2][1], a2, b01); \
    MFMA32(acc[3][0], a3, b00); MFMA32(acc[3][1], a3, b01); \
    MFMA32(acc[0][0], g0, b10); MFMA32(acc[0][1], g0, b11); \
    MFMA32(acc[1][0], g1, b10); MFMA32(acc[1][1], g1, b11); \
    MFMA32(acc[2][0], g2, b10); MFMA32(acc[2][1], g2, b11); \
    MFMA32(acc[3][0], g3, b10); MFMA32(acc[3][1], g3, b11); \
    __builtin_amdgcn_s_setprio(0); }

// ---------------- prep: pack conv weights to [tap][kg][cout][8] fp16 ----------------
__global__ void pack_w(const float* __restrict__ w1, const float* __restrict__ w2,
                       u16* __restrict__ Wp1, u16* __restrict__ Wp2){
  int i = blockIdx.x * 256 + threadIdx.x;
  const int N1 = KW * 12 * FILT;          // 27648
  const int N2 = KW * 32 * FILT;          // 73728
  if (i < N1){
    int tap = i / (12*FILT); int r = i - tap*12*FILT; int kg = r / FILT; int co = r - kg*FILT;
    short8 v;
    #pragma unroll
    for (int e=0;e<8;e++){
      int ci = kg*8 + e;
      float x = (ci < NMEL) ? w1[(co*NMEL + ci)*KW + tap] : 0.f;
      v[e] = (short)f2h(x);
    }
    *(short8*)(Wp1 + (size_t)i*8) = v;
  } else if (i < N1 + N2){
    int j = i - N1;
    int tap = j / (32*FILT); int r = j - tap*32*FILT; int kg = r / FILT; int co = r - kg*FILT;
    short8 v;
    #pragma unroll
    for (int e=0;e<8;e++){
      int ci = kg*8 + e;
      v[e] = (short)f2h(w2[(co*FILT + ci)*KW + tap]);
    }
    *(short8*)(Wp2 + (size_t)j*8) = v;
  }
}

// ---------------- prep: mels -> padded fp16 [B][T+8][104], vectorized ----------------
__global__ void prep_mels(const float* __restrict__ mels, u16* __restrict__ melsPad){
  int idx = blockIdx.x * 256 + threadIdx.x;
  if (idx >= B_*TP8*13) return;
  int ch = idx % 13; int r = idx / 13; int row = r % TP8; int b = r / TP8;
  int t = row - 4;
  short8 v = (short8){0,0,0,0,0,0,0,0};
  if (t >= 0 && t < T_ && ch < 10){
    const float* src = mels + ((size_t)b*T_ + t)*NMEL + ch*8;
    const f32x4 f0 = *(const f32x4*)src;
    const f32x4 f1 = *(const f32x4*)(src+4);
    #pragma unroll
    for (int j=0;j<4;j++){ v[j]=(short)f2h(f0[j]); v[4+j]=(short)f2h(f1[j]); }
  }
  *(short8*)(melsPad + (size_t)idx*8) = v;
}

// ---------------- prep: cumsums (LDS scan), frame->phone, phone->word, zero y1 halos ----------------
__global__ void prep_seg(const int* __restrict__ dur, const int* __restrict__ wpl,
                         int* __restrict__ wcum,
                         int* __restrict__ pid, int* __restrict__ wid,
                         u16* __restrict__ y1Pad){
  int b = blockIdx.x; int tid = threadIdx.x;
  __shared__ int dc[P_];
  __shared__ int wc[W_];
  for (int p=tid; p<P_; p+=256) dc[p] = dur[b*P_+p];
  if (tid < W_) wc[tid] = wpl[b*W_+tid];
  __syncthreads();
  if (tid == 0){ int run=0; for (int p=0;p<P_;p++){ run += dc[p]; dc[p]=run; } }
  if (tid == 64){ int run=0; for (int w=0;w<W_;w++){ run += wc[w]; wc[w]=run; wcum[b*W_+w]=run; } }
  __syncthreads();
  for (int t=tid; t<T_; t+=256){
    int lo=0, hi=P_;
    while (lo < hi){ int mid=(lo+hi)>>1; if (dc[mid] > t) hi=mid; else lo=mid+1; }
    pid[b*T_+t] = lo;
  }
  for (int p=tid; p<P_; p+=256){
    int lo=0, hi=W_;
    while (lo < hi){ int mid=(lo+hi)>>1; if (wc[mid] > p) hi=mid; else lo=mid+1; }
    wid[b*P_+p] = min(lo, W_-1);
  }
  for (int i=tid; i<8*YSTR; i+=256){
    int rr = i / YSTR; int cc = i - rr*YSTR;
    int row = (rr < 4) ? rr : (T_ + rr);
    y1Pad[((size_t)b*TP8 + row)*YSTR + cc] = 0;
  }
}

// ---------------- conv1 + bias + relu + LN1 -> y1Pad fp16 ----------------
// M=256, 512 thr / 8 waves, wave tile 128x64. A in LDS once; B direct
// global->reg. Rotated K-start (role diversity) + setprio MFMA cluster (T5).
__global__ __launch_bounds__(512, 2) void conv1_k(
    const u16* __restrict__ melsPad, const u16* __restrict__ Wp1,
    const float* __restrict__ bias, const float* __restrict__ lng,
    const float* __restrict__ lnb, u16* __restrict__ y1Pad){
  __shared__ __align__(16) u16 sA[27456];   // 54,912 B: 264 rows x 104
  const int tid = threadIdx.x;
  const int wave = tid >> 6, lane = tid & 63, l31 = lane & 31, h = lane >> 5;
  const int rg = wave >> 2, cg = wave & 3;
  const int b = blockIdx.y, t0 = blockIdx.x * 256;

  float bcol[2], gcol[2], btcol[2];
  #pragma unroll
  for (int n=0;n<2;n++){
    int c = cg*64 + n*32 + l31;
    bcol[n]=bias[c]; gcol[n]=lng[c]; btcol[n]=lnb[c];
  }

  {
    const char* gA = (const char*)(melsPad + ((size_t)b*TP8 + t0)*MSTR);
    #pragma unroll
    for (int it=0; it<7; ++it)
      if (it*8192 + tid*16 < 54912)
        __builtin_amdgcn_global_load_lds((gptr_t)(gA + it*8192 + (wave<<10) + (lane<<4)),
                                         (lptr_t)((char*)sA + it*8192 + (wave<<10)), 16, 0, 0);
  }
  const char* gB0 = (const char*)Wp1 + h*4096 + cg*1024 + (l31<<4);
  __syncthreads();   // A resident

  f32x16 acc[4][2] = {};
  const u16* pA0 = sA + ((size_t)(rg*128 + l31))*MSTR + h*8;
  const int start = ((blockIdx.x*5 + wave) % 9) * 3;   // 0,3,...,24

  const char* gBp = gB0 + (size_t)start*16384;
  #pragma unroll 1
  for (int k=start; k<27; ++k){
    const int tap = k/3, s = k - tap*3;
    const u16* pA = pA0 + tap*MSTR + s*32;
    K32_BODY(pA, MSTR)
  }
  gBp = gB0;
  #pragma unroll 1
  for (int k=0; k<start; ++k){
    const int tap = k/3, s = k - tap*3;
    const u16* pA = pA0 + tap*MSTR + s*32;
    K32_BODY(pA, MSTR)
  }

  float* sred  = (float*)sA;          // [256][4]
  float* sred2 = sred + 1024;
  float* smean = sred2 + 1024;        // [256]
  float* srstd = smean + 256;
  __syncthreads();   // all waves done reading sA

  #pragma unroll
  for (int rb=0;rb<4;++rb)
    #pragma unroll
    for (int r=0;r<16;++r){
      float v0 = fmaxf(acc[rb][0][r] + bcol[0], 0.f);
      float v1 = fmaxf(acc[rb][1][r] + bcol[1], 0.f);
      float s = v0+v1, q = v0*v0+v1*v1;
      #pragma unroll
      for (int off=1; off<32; off<<=1){ s += __shfl_xor(s, off); q += __shfl_xor(q, off); }
      if (l31 == 0){ int row = rg*128 + rb*32 + (r&3) + 8*(r>>2) + 4*h;
        sred[row*4+cg]=s; sred2[row*4+cg]=q; }
    }
  __syncthreads();
  if (tid < 256){
    float ss=0.f, qq=0.f;
    #pragma unroll
    for (int w2=0; w2<4; w2++){ ss += sred[tid*4+w2]; qq += sred2[tid*4+w2]; }
    float mean = ss * (1.f/FILT);
    float var  = qq * (1.f/FILT) - mean*mean;
    smean[tid] = mean;
    srstd[tid] = rsqrtf(fmaxf(var, 0.f) + EPS);
  }
  __syncthreads();

  #pragma unroll
  for (int rb=0;rb<4;++rb)
    #pragma unroll
    for (int q=0;q<4;++q){
      const int rbase = rg*128 + rb*32 + q*8 + 4*h;
      float mn0=smean[rbase+0],mn1=smean[rbase+1],mn2=smean[rbase+2],mn3=smean[rbase+3];
      float rs0=srstd[rbase+0],rs1=srstd[rbase+1],rs2=srstd[rbase+2],rs3=srstd[rbase+3];
      #pragma unroll
      for (int cb=0;cb<2;++cb){
        int c = cg*64 + cb*32 + l31;
        float x0 = fmaxf(acc[rb][cb][q*4+0] + bcol[cb], 0.f);
        float x1 = fmaxf(acc[rb][cb][q*4+1] + bcol[cb], 0.f);
        float x2 = fmaxf(acc[rb][cb][q*4+2] + bcol[cb], 0.f);
        float x3 = fmaxf(acc[rb][cb][q*4+3] + bcol[cb], 0.f);
        u16* dst = y1Pad + ((size_t)b*TP8 + 4 + t0 + rbase)*YSTR + c;
        dst[0*YSTR] = f2h((x0-mn0)*rs0*gcol[cb]+btcol[cb]);
        dst[1*YSTR] = f2h((x1-mn1)*rs1*gcol[cb]+btcol[cb]);
        dst[2*YSTR] = f2h((x2-mn2)*rs2*gcol[cb]+btcol[cb]);
        dst[3*YSTR] = f2h((x3-mn3)*rs3*gcol[cb]+btcol[cb]);
      }
    }
}

// ---------------- conv2 + bias + relu + LN2 -> phone-sum atomics ----------------
// M=256, 512 thr / 8 waves, wave tile 128x64. A (139.4 KB) in LDS once;
// B direct global->reg; rotated K-start + setprio MFMA cluster (T5).
__global__ __launch_bounds__(512, 2) void conv2_k(
    const u16* __restrict__ y1Pad, const u16* __restrict__ Wp2,
    const float* __restrict__ bias, const float* __restrict__ lng,
    const float* __restrict__ lnb, const int* __restrict__ pid,
    float* __restrict__ ps){
  __shared__ __align__(16) u16 sA[69696];   // 139,392 B: 264 rows x 264
  __shared__ int pidT[256];
  const int tid = threadIdx.x;
  const int wave = tid >> 6, lane = tid & 63, l31 = lane & 31, h = lane >> 5;
  const int rg = wave >> 2, cg = wave & 3;
  const int b = blockIdx.y, t0 = blockIdx.x * 256;

  float bcol[2], gcol[2], btcol[2];
  #pragma unroll
  for (int n=0;n<2;n++){
    int c = cg*64 + n*32 + l31;
    bcol[n]=bias[c]; gcol[n]=lng[c]; btcol[n]=lnb[c];
  }
  if (tid < 256) pidT[tid] = pid[b*T_ + t0 + tid];

  {
    const char* gA = (const char*)(y1Pad + ((size_t)b*TP8 + t0)*YSTR);
    #pragma unroll
    for (int it=0; it<18; ++it)
      if (it*8192 + tid*16 < 139392)
        __builtin_amdgcn_global_load_lds((gptr_t)(gA + it*8192 + (wave<<10) + (lane<<4)),
                                         (lptr_t)((char*)sA + it*8192 + (wave<<10)), 16, 0, 0);
  }
  const char* gB0 = (const char*)Wp2 + h*4096 + cg*1024 + (l31<<4);
  __syncthreads();   // A resident

  f32x16 acc[4][2] = {};
  const u16* pA0 = sA + ((size_t)(rg*128 + l31))*YSTR + h*8;
  const int start = ((blockIdx.x*5 + wave) & 7) * 9;   // 0,9,...,63

  const char* gBp = gB0 + (size_t)start*16384;
  #pragma unroll 2
  for (int k=start; k<72; ++k){
    const int tap = k>>3, sg = k&7;
    const u16* pA = pA0 + tap*YSTR + sg*32;
    K32_BODY(pA, YSTR)
  }
  gBp = gB0;
  #pragma unroll 2
  for (int k=0; k<start; ++k){
    const int tap = k>>3, sg = k&7;
    const u16* pA = pA0 + tap*YSTR + sg*32;
    K32_BODY(pA, YSTR)
  }

  float* sred  = (float*)sA;          // [256][4]
  float* sred2 = sred + 1024;
  float* smean = sred2 + 1024;        // [256]
  float* srstd = smean + 256;
  __syncthreads();   // all waves done reading sA

  #pragma unroll
  for (int rb=0;rb<4;++rb)
    #pragma unroll
    for (int r=0;r<16;++r){
      float v0 = fmaxf(acc[rb][0][r] + bcol[0], 0.f);
      float v1 = fmaxf(acc[rb][1][r] + bcol[1], 0.f);
      float s = v0+v1, q = v0*v0+v1*v1;
      #pragma unroll
      for (int off=1; off<32; off<<=1){ s += __shfl_xor(s, off); q += __shfl_xor(q, off); }
      if (l31 == 0){ int row = rg*128 + rb*32 + (r&3) + 8*(r>>2) + 4*h;
        sred[row*4+cg]=s; sred2[row*4+cg]=q; }
    }
  __syncthreads();
  if (tid < 256){
    float ss=0.f, qq=0.f;
    #pragma unroll
    for (int w2=0; w2<4; w2++){ ss += sred[tid*4+w2]; qq += sred2[tid*4+w2]; }
    float mean = ss * (1.f/FILT);
    float var  = qq * (1.f/FILT) - mean*mean;
    smean[tid] = mean;
    srstd[tid] = rsqrtf(fmaxf(var, 0.f) + EPS);
  }
  __syncthreads();

  #pragma unroll
  for (int rb=0;rb<4;++rb)
    #pragma unroll
    for (int q=0;q<4;++q){
      const int rbase = rg*128 + rb*32 + q*8 + 4*h;
      int p0v = pidT[rbase]; int fold = (p0v == pidT[rbase+3]);
      float mn0=smean[rbase+0],mn1=smean[rbase+1],mn2=smean[rbase+2],mn3=smean[rbase+3];
      float rs0=srstd[rbase+0],rs1=srstd[rbase+1],rs2=srstd[rbase+2],rs3=srstd[rbase+3];
      int pp = __shfl_xor(p0v, 32); int fp = __shfl_xor(fold, 32);
      #pragma unroll
      for (int cb=0;cb<2;++cb){
        int c = cg*64 + cb*32 + l31;
        float x0 = fmaxf(acc[rb][cb][q*4+0] + bcol[cb], 0.f);
        float x1 = fmaxf(acc[rb][cb][q*4+1] + bcol[cb], 0.f);
        float x2 = fmaxf(acc[rb][cb][q*4+2] + bcol[cb], 0.f);
        float x3 = fmaxf(acc[rb][cb][q*4+3] + bcol[cb], 0.f);
        float o0 = (x0-mn0)*rs0*gcol[cb]+btcol[cb];
        float o1 = (x1-mn1)*rs1*gcol[cb]+btcol[cb];
        float o2 = (x2-mn2)*rs2*gcol[cb]+btcol[cb];
        float o3 = (x3-mn3)*rs3*gcol[cb]+btcol[cb];
        float s4 = fold ? (o0+o1+o2+o3) : 0.f;
        float sp = __shfl_xor(s4, 32);
        float* basep = ps + (size_t)b*P_*FILT;
        if (fold){
          if (p0v < P_){
            if (fp && pp == p0v){ if (h == 0) atomicAdd(basep + (size_t)p0v*FILT + c, s4 + sp); }
            else atomicAdd(basep + (size_t)p0v*FILT + c, s4);
          }
        } else {
          int pj;
          pj = pidT[rbase+0]; if (pj < P_) atomicAdd(basep + (size_t)pj*FILT + c, o0);
          pj = pidT[rbase+1]; if (pj < P_) atomicAdd(basep + (size_t)pj*FILT + c, o1);
          pj = pidT[rbase+2]; if (pj < P_) atomicAdd(basep + (size_t)pj*FILT + c, o2);
          pj = pidT[rbase+3]; if (pj < P_) atomicAdd(basep + (size_t)pj*FILT + c, o3);
        }
      }
    }
}

// ---------------- word pooling + MLP: 8 words per block ----------------
#define WPB 8
__global__ __launch_bounds__(256) void word_k(
    const float* __restrict__ ps, const int* __restrict__ dur,
    const int* __restrict__ wcum, const int* __restrict__ wpl,
    const float* __restrict__ w1, const float* __restrict__ b1,
    const float* __restrict__ w2, const float* __restrict__ b2,
    float* __restrict__ wemb){
  int b = blockIdx.y, wg = blockIdx.x * WPB, tid = threadIdx.x;
  __shared__ float wvS[WPB][FILT];
  __shared__ float h1S[WPB][FILT];
  #pragma unroll
  for (int k=0;k<WPB;k++){
    int w = wg + k;
    int p1 = wcum[b*W_ + w]; int p0 = (w == 0) ? 0 : wcum[b*W_ + w - 1];
    if (p1 > P_) p1 = P_;
    int len = wpl[b*W_ + w];
    float a = 0.f;
    for (int p = p0; p < p1; ++p){
      int d = dur[b*P_ + p]; d = d < 1 ? 1 : d;
      a += ps[((size_t)(b*P_ + p))*FILT + tid] / (float)d;
    }
    wvS[k][tid] = a / (float)(len < 1 ? 1 : len);
  }
  __syncthreads();
  float acc[WPB];
  #pragma unroll
  for (int k=0;k<WPB;k++) acc[k] = b1[tid];
  for (int i=0;i<FILT;i++){
    float wcol = w1[i*FILT + tid];
    #pragma unroll
    for (int k=0;k<WPB;k++) acc[k] += wvS[k][i] * wcol;
  }
  #pragma unroll
  for (int k=0;k<WPB;k++) h1S[k][tid] = fmaxf(acc[k], 0.f);
  __syncthreads();
  int c = tid & 63, kq = tid >> 6;
  #pragma unroll
  for (int kk=kq; kk<WPB; kk+=4){
    float u = b2[c];
    for (int i=0;i<FILT;i++) u += h1S[kk][i] * w2[i*PDIM + c];
    wemb[((size_t)(b*W_ + wg + kk))*PDIM + c] = fmaxf(u, 0.f);
  }
}

// ---------------- expand words -> phones + mask (float4) ----------------
__global__ void expand_k(const float* __restrict__ wemb, const int* __restrict__ wid,
                         const unsigned char* __restrict__ mask, float* __restrict__ out){
  int idx = blockIdx.x * 256 + threadIdx.x;
  if (idx >= B_*P_*16) return;
  int q = idx & 15; int p = (idx >> 4) & 511; int bb = idx >> 13;
  int w = wid[bb*P_ + p];
  f32x4 v = *(const f32x4*)(wemb + ((size_t)(bb*W_ + w))*PDIM + q*4);
  if (mask[bb*P_ + p]) v = (f32x4){0.f,0.f,0.f,0.f};
  *(f32x4*)(out + (size_t)idx*4) = v;
}

extern "C" void kernel_launch(void* const* d_in, const int* in_sizes, int n_in,
                              void* d_out, int out_size, void* d_ws, size_t ws_size,
                              hipStream_t stream) {
  const unsigned char* mask = (const unsigned char*)d_in[0];
  const float* mels = (const float*)d_in[1];
  const int*   dur  = (const int*)d_in[3];
  const int*   wpl  = (const int*)d_in[4];
  const float* c1w  = (const float*)d_in[5];
  const float* c1b  = (const float*)d_in[6];
  const float* l1g  = (const float*)d_in[7];
  const float* l1b  = (const float*)d_in[8];
  const float* c2w  = (const float*)d_in[9];
  const float* c2b  = (const float*)d_in[10];
  const float* l2g  = (const float*)d_in[11];
  const float* l2b  = (const float*)d_in[12];
  const float* w1   = (const float*)d_in[13];
  const float* b1   = (const float*)d_in[14];
  const float* w2   = (const float*)d_in[15];
  const float* b2   = (const float*)d_in[16];

  char* ws = (char*)d_ws;
  size_t off = 0;
  auto alloc = [&](size_t bytes){ void* p = ws + off; off += (bytes + 255) & ~(size_t)255; return p; };
  u16* melsPad = (u16*)alloc((size_t)B_*TP8*MSTR*2 + 32768);
  u16* y1Pad   = (u16*)alloc((size_t)B_*TP8*YSTR*2 + 32768);
  u16* Wp1     = (u16*)alloc((size_t)KW*12*FILT*8*2 + 32768);
  u16* Wp2     = (u16*)alloc((size_t)KW*32*FILT*8*2 + 32768);
  int* wcum    = (int*)alloc((size_t)B_*W_*4);
  int* pid     = (int*)alloc((size_t)B_*T_*4);
  int* wid     = (int*)alloc((size_t)B_*P_*4);
  float* psum  = (float*)alloc((size_t)B_*P_*FILT*4);
  float* wemb  = (float*)alloc((size_t)B_*W_*PDIM*4);

  hipMemsetAsync(psum, 0, (size_t)B_*P_*FILT*4, stream);
  pack_w<<<(KW*12*FILT + KW*32*FILT + 255)/256, 256, 0, stream>>>(c1w, c2w, Wp1, Wp2);
  prep_mels<<<(B_*TP8*13 + 255)/256, 256, 0, stream>>>(mels, melsPad);
  prep_seg<<<B_, 256, 0, stream>>>(dur, wpl, wcum, pid, wid, y1Pad);
  conv1_k<<<dim3(T_/256, B_), 512, 0, stream>>>(melsPad, Wp1, c1b, l1g, l1b, y1Pad);
  conv2_k<<<dim3(T_/256, B_), 512, 0, stream>>>(y1Pad, Wp2, c2b, l2g, l2b, pid, psum);
  word_k<<<dim3(W_/WPB, B_), 256, 0, stream>>>(psum, dur, wcum, wpl, w1, b1, w2, b2, wemb);
  expand_k<<<(B_*P_*16 + 255)/256, 256, 0, stream>>>(wemb, wid, mask, (float*)d_out);
}

// Round 17
// 325.901 us; speedup vs baseline: 1.1382x; 1.1284x over previous
//
#include <hip/hip_runtime.h>
#include <hip/hip_fp16.h>
#include <stdint.h>

#define B_ 32
#define T_ 4096
#define P_ 512
#define W_ 128
#define NMEL 80
#define FILT 256
#define PDIM 64
#define KW 9
#define TP8 (T_ + 8)
#define MSTR 104
#define YSTR 264
#define EPS 1e-5f

typedef unsigned short u16;
typedef __attribute__((ext_vector_type(8))) short short8;
typedef __attribute__((ext_vector_type(8))) _Float16 half8;
typedef __attribute__((ext_vector_type(4))) float f32x4;
typedef __attribute__((ext_vector_type(16))) float f32x16;

typedef const __attribute__((address_space(1))) uint32_t* gptr_t;
typedef __attribute__((address_space(3))) uint32_t* lptr_t;

__device__ __forceinline__ u16 f2h(float v){ return __half_as_ushort(__float2half(v)); }

#define MFMA32(accv, av, bv) \
  accv = __builtin_amdgcn_mfma_f32_32x32x16_f16((av), (bv), (accv), 0, 0, 0)

// 16 MFMAs for one k32 step: A[4][2] strips x s2, Bv[2][2] s2 x cb
#define MFMASET(A, Bv) { \
  MFMA32(acc[0][0][0], A[0][0], Bv[0][0]); MFMA32(acc[0][0][1], A[0][0], Bv[0][1]); \
  MFMA32(acc[0][1][0], A[1][0], Bv[0][0]); MFMA32(acc[0][1][1], A[1][0], Bv[0][1]); \
  MFMA32(acc[1][0][0], A[2][0], Bv[0][0]); MFMA32(acc[1][0][1], A[2][0], Bv[0][1]); \
  MFMA32(acc[1][1][0], A[3][0], Bv[0][0]); MFMA32(acc[1][1][1], A[3][0], Bv[0][1]); \
  MFMA32(acc[0][0][0], A[0][1], Bv[1][0]); MFMA32(acc[0][0][1], A[0][1], Bv[1][1]); \
  MFMA32(acc[0][1][0], A[1][1], Bv[1][0]); MFMA32(acc[0][1][1], A[1][1], Bv[1][1]); \
  MFMA32(acc[1][0][0], A[2][1], Bv[1][0]); MFMA32(acc[1][0][1], A[2][1], Bv[1][1]); \
  MFMA32(acc[1][1][0], A[3][1], Bv[1][0]); MFMA32(acc[1][1][1], A[3][1], Bv[1][1]); }

// ---------------- merged prep: seg-scan | pack weights | pad mels | zero psum ----------------
#define PREP_SEG_BLKS   32
#define PACKW_ITEMS     (KW*12*FILT + KW*32*FILT)           // 101376
#define PACKW_BLKS      ((PACKW_ITEMS + 255)/256)           // 396
#define MELS_ITEMS      (B_*TP8*13)
#define MELS_BLKS       ((MELS_ITEMS + 255)/256)
#define PSUM_ITEMS      (B_*P_*FILT/4)                      // float4 count
#define PSUM_BLKS       ((PSUM_ITEMS + 255)/256)

__global__ __launch_bounds__(256) void prep_all(
    const int* __restrict__ dur, const int* __restrict__ wpl,
    int* __restrict__ wcum, int* __restrict__ pid, int* __restrict__ wid,
    u16* __restrict__ y1Pad,
    const float* __restrict__ w1, const float* __restrict__ w2,
    u16* __restrict__ Wp1, u16* __restrict__ Wp2,
    const float* __restrict__ mels, u16* __restrict__ melsPad,
    float* __restrict__ psum){
  const int blk = blockIdx.x;
  const int tid = threadIdx.x;

  if (blk < PREP_SEG_BLKS){
    // ---- per-batch segment prep ----
    int b = blk;
    __shared__ int dc[P_];
    __shared__ int wc[W_];
    for (int p=tid; p<P_; p+=256) dc[p] = dur[b*P_+p];
    if (tid < W_) wc[tid] = wpl[b*W_+tid];
    __syncthreads();
    if (tid == 0){ int run=0; for (int p=0;p<P_;p++){ run += dc[p]; dc[p]=run; } }
    if (tid == 64){ int run=0; for (int w=0;w<W_;w++){ run += wc[w]; wc[w]=run; wcum[b*W_+w]=run; } }
    __syncthreads();
    for (int t=tid; t<T_; t+=256){
      int lo=0, hi=P_;
      while (lo < hi){ int mid=(lo+hi)>>1; if (dc[mid] > t) hi=mid; else lo=mid+1; }
      pid[b*T_+t] = lo;
    }
    for (int p=tid; p<P_; p+=256){
      int lo=0, hi=W_;
      while (lo < hi){ int mid=(lo+hi)>>1; if (wc[mid] > p) hi=mid; else lo=mid+1; }
      wid[b*P_+p] = min(lo, W_-1);
    }
    for (int i=tid; i<8*YSTR; i+=256){
      int rr = i / YSTR; int cc = i - rr*YSTR;
      int row = (rr < 4) ? rr : (T_ + rr);
      y1Pad[((size_t)b*TP8 + row)*YSTR + cc] = 0;
    }
    return;
  }
  if (blk < PREP_SEG_BLKS + PACKW_BLKS){
    // ---- pack conv weights ----
    int i = (blk - PREP_SEG_BLKS)*256 + tid;
    const int N1 = KW * 12 * FILT;
    const int N2 = KW * 32 * FILT;
    if (i < N1){
      int tap = i / (12*FILT); int r = i - tap*12*FILT; int kg = r / FILT; int co = r - kg*FILT;
      short8 v;
      #pragma unroll
      for (int e=0;e<8;e++){
        int ci = kg*8 + e;
        float x = (ci < NMEL) ? w1[(co*NMEL + ci)*KW + tap] : 0.f;
        v[e] = (short)f2h(x);
      }
      *(short8*)(Wp1 + (size_t)i*8) = v;
    } else if (i < N1 + N2){
      int j = i - N1;
      int tap = j / (32*FILT); int r = j - tap*32*FILT; int kg = r / FILT; int co = r - kg*FILT;
      short8 v;
      #pragma unroll
      for (int e=0;e<8;e++){
        int ci = kg*8 + e;
        v[e] = (short)f2h(w2[(co*FILT + ci)*KW + tap]);
      }
      *(short8*)(Wp2 + (size_t)j*8) = v;
    }
    return;
  }
  if (blk < PREP_SEG_BLKS + PACKW_BLKS + MELS_BLKS){
    // ---- mels -> padded fp16 ----
    int idx = (blk - PREP_SEG_BLKS - PACKW_BLKS)*256 + tid;
    if (idx >= MELS_ITEMS) return;
    int ch = idx % 13; int r = idx / 13; int row = r % TP8; int b = r / TP8;
    int t = row - 4;
    short8 v = (short8){0,0,0,0,0,0,0,0};
    if (t >= 0 && t < T_ && ch < 10){
      const float* src = mels + ((size_t)b*T_ + t)*NMEL + ch*8;
      const f32x4 f0 = *(const f32x4*)src;
      const f32x4 f1 = *(const f32x4*)(src+4);
      #pragma unroll
      for (int j=0;j<4;j++){ v[j]=(short)f2h(f0[j]); v[4+j]=(short)f2h(f1[j]); }
    }
    *(short8*)(melsPad + (size_t)idx*8) = v;
    return;
  }
  {
    // ---- zero psum (float4) ----
    int idx = (blk - PREP_SEG_BLKS - PACKW_BLKS - MELS_BLKS)*256 + tid;
    if (idx < PSUM_ITEMS)
      *( (f32x4*)psum + idx ) = (f32x4){0.f,0.f,0.f,0.f};
  }
}

// ---------------- conv1 + bias + relu + LN1 -> y1Pad fp16 ----------------
// M=128, 256 thr / 4 waves (wave = 64-cout group). A in LDS once; B direct
// global->reg. Builtin (non-volatile) MFMA -> compiler interleaves loads.
__global__ __launch_bounds__(256, 2) void conv1_k(
    const u16* __restrict__ melsPad, const u16* __restrict__ Wp1,
    const float* __restrict__ bias, const float* __restrict__ lng,
    const float* __restrict__ lnb, u16* __restrict__ y1Pad){
  __shared__ __align__(16) u16 sA[14144];   // 28,288 B: 136 rows x 104
  __shared__ float sred[512], sred2[512], smean[128], srstd[128];
  const int tid = threadIdx.x;
  const int cg = tid >> 6, lane = tid & 63, l31 = lane & 31, h = lane >> 5;
  const int b = blockIdx.y, t0 = blockIdx.x * 128;

  float bcol[2], gcol[2], btcol[2];
  #pragma unroll
  for (int n=0;n<2;n++){
    int c = cg*64 + n*32 + l31;
    bcol[n]=bias[c]; gcol[n]=lng[c]; btcol[n]=lnb[c];
  }

  {
    const char* gA = (const char*)(melsPad + ((size_t)b*TP8 + t0)*MSTR);
    #pragma unroll
    for (int it=0; it<7; ++it)
      if (it*4096 + tid*16 < 28288)
        __builtin_amdgcn_global_load_lds((gptr_t)(gA + it*4096 + (cg<<10) + (lane<<4)),
                                         (lptr_t)((char*)sA + it*4096 + (cg<<10)), 16, 0, 0);
  }

  const char* gB = (const char*)Wp1 + h*4096 + cg*1024 + (l31<<4);
#define LOADB1(cc, D) { const char* nb_ = gB + (size_t)(cc)*16384; \
    D[0][0]=*(const half8*)(nb_);      D[0][1]=*(const half8*)(nb_+512); \
    D[1][0]=*(const half8*)(nb_+8192); D[1][1]=*(const half8*)(nb_+8704); }
#define LOADA1(cc, A) { const int tap_=(cc)/3, s_=(cc)%3; \
    const u16* pA_ = sA + (l31 + tap_)*MSTR + s_*32 + h*8; \
    A[0][0]=*(const half8*)(pA_);             A[0][1]=*(const half8*)(pA_+16); \
    A[1][0]=*(const half8*)(pA_+32*MSTR);     A[1][1]=*(const half8*)(pA_+32*MSTR+16); \
    A[2][0]=*(const half8*)(pA_+64*MSTR);     A[2][1]=*(const half8*)(pA_+64*MSTR+16); \
    A[3][0]=*(const half8*)(pA_+96*MSTR);     A[3][1]=*(const half8*)(pA_+96*MSTR+16); }

  half8 B0[2][2], B1[2][2], A0[4][2], A1[4][2];
  LOADB1(0, B0)
  __syncthreads();   // A resident in LDS; B0 valid
  LOADA1(0, A0)

  f32x16 acc[2][2][2] = {};

  #pragma unroll 1
  for (int c2=0; c2<13; ++c2){
    const int cc = 2*c2;
    LOADA1(cc+1, A1) LOADB1(cc+1, B1)
    MFMASET(A0, B0)
    LOADA1(cc+2, A0) LOADB1(cc+2, B0)
    MFMASET(A1, B1)
  }
  MFMASET(A0, B0)    // cc = 26

  #pragma unroll
  for (int st=0;st<2;++st)
    #pragma unroll
    for (int rb=0;rb<2;++rb)
      #pragma unroll
      for (int r=0;r<16;++r){
        float v0 = fmaxf(acc[st][rb][0][r] + bcol[0], 0.f);
        float v1 = fmaxf(acc[st][rb][1][r] + bcol[1], 0.f);
        float s = v0+v1, q = v0*v0+v1*v1;
        #pragma unroll
        for (int off=1; off<32; off<<=1){ s += __shfl_xor(s, off); q += __shfl_xor(q, off); }
        if (l31 == 0){ int row = st*64 + rb*32 + (r&3) + 8*(r>>2) + 4*h;
          sred[row*4+cg]=s; sred2[row*4+cg]=q; }
      }
  __syncthreads();
  if (tid < 128){
    float ss=0.f, qq=0.f;
    #pragma unroll
    for (int w2=0; w2<4; w2++){ ss += sred[tid*4+w2]; qq += sred2[tid*4+w2]; }
    float mean = ss * (1.f/FILT);
    float var  = qq * (1.f/FILT) - mean*mean;
    smean[tid] = mean;
    srstd[tid] = rsqrtf(fmaxf(var, 0.f) + EPS);
  }
  __syncthreads();

  #pragma unroll
  for (int st=0;st<2;++st)
    #pragma unroll
    for (int rb=0;rb<2;++rb)
      #pragma unroll
      for (int q=0;q<4;++q){
        const int rbase = st*64 + rb*32 + q*8 + 4*h;
        float mn0=smean[rbase+0],mn1=smean[rbase+1],mn2=smean[rbase+2],mn3=smean[rbase+3];
        float rs0=srstd[rbase+0],rs1=srstd[rbase+1],rs2=srstd[rbase+2],rs3=srstd[rbase+3];
        #pragma unroll
        for (int cb=0;cb<2;++cb){
          int c = cg*64 + cb*32 + l31;
          float x0 = fmaxf(acc[st][rb][cb][q*4+0] + bcol[cb], 0.f);
          float x1 = fmaxf(acc[st][rb][cb][q*4+1] + bcol[cb], 0.f);
          float x2 = fmaxf(acc[st][rb][cb][q*4+2] + bcol[cb], 0.f);
          float x3 = fmaxf(acc[st][rb][cb][q*4+3] + bcol[cb], 0.f);
          u16* dst = y1Pad + ((size_t)b*TP8 + 4 + t0 + rbase)*YSTR + c;
          dst[0*YSTR] = f2h((x0-mn0)*rs0*gcol[cb]+btcol[cb]);
          dst[1*YSTR] = f2h((x1-mn1)*rs1*gcol[cb]+btcol[cb]);
          dst[2*YSTR] = f2h((x2-mn2)*rs2*gcol[cb]+btcol[cb]);
          dst[3*YSTR] = f2h((x3-mn3)*rs3*gcol[cb]+btcol[cb]);
        }
      }
}

// ---------------- conv2 + bias + relu + LN2 -> phone-sum atomics ----------------
// M=128, 256 thr / 4 waves. A in LDS once; B direct global->reg.
// Builtin MFMA, 72 k32-iters = 36 pairs.
__global__ __launch_bounds__(256, 2) void conv2_k(
    const u16* __restrict__ y1Pad, const u16* __restrict__ Wp2,
    const float* __restrict__ bias, const float* __restrict__ lng,
    const float* __restrict__ lnb, const int* __restrict__ pid,
    float* __restrict__ ps){
  __shared__ __align__(16) u16 sA[35904];   // 71,808 B: 136 rows x 264
  __shared__ float sred[512], sred2[512], smean[128], srstd[128];
  __shared__ int pidT[128];
  const int tid = threadIdx.x;
  const int cg = tid >> 6, lane = tid & 63, l31 = lane & 31, h = lane >> 5;
  const int b = blockIdx.y, t0 = blockIdx.x * 128;

  float bcol[2], gcol[2], btcol[2];
  #pragma unroll
  for (int n=0;n<2;n++){
    int c = cg*64 + n*32 + l31;
    bcol[n]=bias[c]; gcol[n]=lng[c]; btcol[n]=lnb[c];
  }
  if (tid < 128) pidT[tid] = pid[b*T_ + t0 + tid];

  {
    const char* gA = (const char*)(y1Pad + ((size_t)b*TP8 + t0)*YSTR);
    #pragma unroll
    for (int it=0; it<18; ++it)
      if (it*4096 + tid*16 < 71808)
        __builtin_amdgcn_global_load_lds((gptr_t)(gA + it*4096 + (cg<<10) + (lane<<4)),
                                         (lptr_t)((char*)sA + it*4096 + (cg<<10)), 16, 0, 0);
  }

  const char* gB = (const char*)Wp2 + h*4096 + cg*1024 + (l31<<4);
#define LOADB2(cc, D) { const char* nb_ = gB + (size_t)(cc)*16384; \
    D[0][0]=*(const half8*)(nb_);      D[0][1]=*(const half8*)(nb_+512); \
    D[1][0]=*(const half8*)(nb_+8192); D[1][1]=*(const half8*)(nb_+8704); }
#define LOADA2(cc, A) { const int tap_=(cc)>>3, sg_=(cc)&7; \
    const u16* pA_ = sA + (l31 + tap_)*YSTR + sg_*32 + h*8; \
    A[0][0]=*(const half8*)(pA_);             A[0][1]=*(const half8*)(pA_+16); \
    A[1][0]=*(const half8*)(pA_+32*YSTR);     A[1][1]=*(const half8*)(pA_+32*YSTR+16); \
    A[2][0]=*(const half8*)(pA_+64*YSTR);     A[2][1]=*(const half8*)(pA_+64*YSTR+16); \
    A[3][0]=*(const half8*)(pA_+96*YSTR);     A[3][1]=*(const half8*)(pA_+96*YSTR+16); }

  half8 B0[2][2], B1[2][2], A0[4][2], A1[4][2];
  LOADB2(0, B0)
  __syncthreads();   // A resident; B0 valid
  LOADA2(0, A0)

  f32x16 acc[2][2][2] = {};

  #pragma unroll 1
  for (int c2=0; c2<36; ++c2){
    const int cc = 2*c2;
    LOADA2(cc+1, A1) LOADB2(cc+1, B1)
    MFMASET(A0, B0)
    if (c2 < 35){ LOADA2(cc+2, A0) LOADB2(cc+2, B0) }
    MFMASET(A1, B1)
  }

  #pragma unroll
  for (int st=0;st<2;++st)
    #pragma unroll
    for (int rb=0;rb<2;++rb)
      #pragma unroll
      for (int r=0;r<16;++r){
        float v0 = fmaxf(acc[st][rb][0][r] + bcol[0], 0.f);
        float v1 = fmaxf(acc[st][rb][1][r] + bcol[1], 0.f);
        float s = v0+v1, q = v0*v0+v1*v1;
        #pragma unroll
        for (int off=1; off<32; off<<=1){ s += __shfl_xor(s, off); q += __shfl_xor(q, off); }
        if (l31 == 0){ int row = st*64 + rb*32 + (r&3) + 8*(r>>2) + 4*h;
          sred[row*4+cg]=s; sred2[row*4+cg]=q; }
      }
  __syncthreads();
  if (tid < 128){
    float ss=0.f, qq=0.f;
    #pragma unroll
    for (int w2=0; w2<4; w2++){ ss += sred[tid*4+w2]; qq += sred2[tid*4+w2]; }
    float mean = ss * (1.f/FILT);
    float var  = qq * (1.f/FILT) - mean*mean;
    smean[tid] = mean;
    srstd[tid] = rsqrtf(fmaxf(var, 0.f) + EPS);
  }
  __syncthreads();

  #pragma unroll
  for (int st=0;st<2;++st)
    #pragma unroll
    for (int rb=0;rb<2;++rb)
      #pragma unroll
      for (int q=0;q<4;++q){
        const int rbase = st*64 + rb*32 + q*8 + 4*h;
        int p0v = pidT[rbase]; int fold = (p0v == pidT[rbase+3]);
        float mn0=smean[rbase+0],mn1=smean[rbase+1],mn2=smean[rbase+2],mn3=smean[rbase+3];
        float rs0=srstd[rbase+0],rs1=srstd[rbase+1],rs2=srstd[rbase+2],rs3=srstd[rbase+3];
        int pp = __shfl_xor(p0v, 32); int fp = __shfl_xor(fold, 32);
        #pragma unroll
        for (int cb=0;cb<2;++cb){
          int c = cg*64 + cb*32 + l31;
          float x0 = fmaxf(acc[st][rb][cb][q*4+0] + bcol[cb], 0.f);
          float x1 = fmaxf(acc[st][rb][cb][q*4+1] + bcol[cb], 0.f);
          float x2 = fmaxf(acc[st][rb][cb][q*4+2] + bcol[cb], 0.f);
          float x3 = fmaxf(acc[st][rb][cb][q*4+3] + bcol[cb], 0.f);
          float o0 = (x0-mn0)*rs0*gcol[cb]+btcol[cb];
          float o1 = (x1-mn1)*rs1*gcol[cb]+btcol[cb];
          float o2 = (x2-mn2)*rs2*gcol[cb]+btcol[cb];
          float o3 = (x3-mn3)*rs3*gcol[cb]+btcol[cb];
          float s4 = fold ? (o0+o1+o2+o3) : 0.f;
          float sp = __shfl_xor(s4, 32);
          float* basep = ps + (size_t)b*P_*FILT;
          if (fold){
            if (p0v < P_){
              if (fp && pp == p0v){ if (h == 0) atomicAdd(basep + (size_t)p0v*FILT + c, s4 + sp); }
              else atomicAdd(basep + (size_t)p0v*FILT + c, s4);
            }
          } else {
            int pj;
            pj = pidT[rbase+0]; if (pj < P_) atomicAdd(basep + (size_t)pj*FILT + c, o0);
            pj = pidT[rbase+1]; if (pj < P_) atomicAdd(basep + (size_t)pj*FILT + c, o1);
            pj = pidT[rbase+2]; if (pj < P_) atomicAdd(basep + (size_t)pj*FILT + c, o2);
            pj = pidT[rbase+3]; if (pj < P_) atomicAdd(basep + (size_t)pj*FILT + c, o3);
          }
        }
      }
}

// ---------------- word pooling + MLP: 8 words per block ----------------
#define WPB 8
__global__ __launch_bounds__(256) void word_k(
    const float* __restrict__ ps, const int* __restrict__ dur,
    const int* __restrict__ wcum, const int* __restrict__ wpl,
    const float* __restrict__ w1, const float* __restrict__ b1,
    const float* __restrict__ w2, const float* __restrict__ b2,
    float* __restrict__ wemb){
  int b = blockIdx.y, wg = blockIdx.x * WPB, tid = threadIdx.x;
  __shared__ float wvS[WPB][FILT];
  __shared__ float h1S[WPB][FILT];
  #pragma unroll
  for (int k=0;k<WPB;k++){
    int w = wg + k;
    int p1 = wcum[b*W_ + w]; int p0 = (w == 0) ? 0 : wcum[b*W_ + w - 1];
    if (p1 > P_) p1 = P_;
    int len = wpl[b*W_ + w];
    float a = 0.f;
    for (int p = p0; p < p1; ++p){
      int d = dur[b*P_ + p]; d = d < 1 ? 1 : d;
      a += ps[((size_t)(b*P_ + p))*FILT + tid] / (float)d;
    }
    wvS[k][tid] = a / (float)(len < 1 ? 1 : len);
  }
  __syncthreads();
  float acc[WPB];
  #pragma unroll
  for (int k=0;k<WPB;k++) acc[k] = b1[tid];
  for (int i=0;i<FILT;i++){
    float wcol = w1[i*FILT + tid];
    #pragma unroll
    for (int k=0;k<WPB;k++) acc[k] += wvS[k][i] * wcol;
  }
  #pragma unroll
  for (int k=0;k<WPB;k++) h1S[k][tid] = fmaxf(acc[k], 0.f);
  __syncthreads();
  int c = tid & 63, kq = tid >> 6;
  #pragma unroll
  for (int kk=kq; kk<WPB; kk+=4){
    float u = b2[c];
    for (int i=0;i<FILT;i++) u += h1S[kk][i] * w2[i*PDIM + c];
    wemb[((size_t)(b*W_ + wg + kk))*PDIM + c] = fmaxf(u, 0.f);
  }
}

// ---------------- expand words -> phones + mask (float4) ----------------
__global__ void expand_k(const float* __restrict__ wemb, const int* __restrict__ wid,
                         const unsigned char* __restrict__ mask, float* __restrict__ out){
  int idx = blockIdx.x * 256 + threadIdx.x;
  if (idx >= B_*P_*16) return;
  int q = idx & 15; int p = (idx >> 4) & 511; int bb = idx >> 13;
  int w = wid[bb*P_ + p];
  f32x4 v = *(const f32x4*)(wemb + ((size_t)(bb*W_ + w))*PDIM + q*4);
  if (mask[bb*P_ + p]) v = (f32x4){0.f,0.f,0.f,0.f};
  *(f32x4*)(out + (size_t)idx*4) = v;
}

extern "C" void kernel_launch(void* const* d_in, const int* in_sizes, int n_in,
                              void* d_out, int out_size, void* d_ws, size_t ws_size,
                              hipStream_t stream) {
  const unsigned char* mask = (const unsigned char*)d_in[0];
  const float* mels = (const float*)d_in[1];
  const int*   dur  = (const int*)d_in[3];
  const int*   wpl  = (const int*)d_in[4];
  const float* c1w  = (const float*)d_in[5];
  const float* c1b  = (const float*)d_in[6];
  const float* l1g  = (const float*)d_in[7];
  const float* l1b  = (const float*)d_in[8];
  const float* c2w  = (const float*)d_in[9];
  const float* c2b  = (const float*)d_in[10];
  const float* l2g  = (const float*)d_in[11];
  const float* l2b  = (const float*)d_in[12];
  const float* w1   = (const float*)d_in[13];
  const float* b1   = (const float*)d_in[14];
  const float* w2   = (const float*)d_in[15];
  const float* b2   = (const float*)d_in[16];

  char* ws = (char*)d_ws;
  size_t off = 0;
  auto alloc = [&](size_t bytes){ void* p = ws + off; off += (bytes + 255) & ~(size_t)255; return p; };
  u16* melsPad = (u16*)alloc((size_t)B_*TP8*MSTR*2 + 32768);
  u16* y1Pad   = (u16*)alloc((size_t)B_*TP8*YSTR*2 + 32768);
  u16* Wp1     = (u16*)alloc((size_t)KW*12*FILT*8*2 + 32768);
  u16* Wp2     = (u16*)alloc((size_t)KW*32*FILT*8*2 + 32768);
  int* wcum    = (int*)alloc((size_t)B_*W_*4);
  int* pid     = (int*)alloc((size_t)B_*T_*4);
  int* wid     = (int*)alloc((size_t)B_*P_*4);
  float* psum  = (float*)alloc((size_t)B_*P_*FILT*4);
  float* wemb  = (float*)alloc((size_t)B_*W_*PDIM*4);

  const int prep_blocks = PREP_SEG_BLKS + PACKW_BLKS + MELS_BLKS + PSUM_BLKS;
  prep_all<<<prep_blocks, 256, 0, stream>>>(dur, wpl, wcum, pid, wid, y1Pad,
                                            c1w, c2w, Wp1, Wp2, mels, melsPad, psum);
  conv1_k<<<dim3(T_/128, B_), 256, 0, stream>>>(melsPad, Wp1, c1b, l1g, l1b, y1Pad);
  conv2_k<<<dim3(T_/128, B_), 256, 0, stream>>>(y1Pad, Wp2, c2b, l2g, l2b, pid, psum);
  word_k<<<dim3(W_/WPB, B_), 256, 0, stream>>>(psum, dur, wcum, wpl, w1, b1, w2, b2, wemb);
  expand_k<<<(B_*P_*16 + 255)/256, 256, 0, stream>>>(wemb, wid, mask, (float*)d_out);
}